// Round 8
// baseline (466.150 us; speedup 1.0000x reference)
//
#include <hip/hip_runtime.h>
#include <hip/hip_bf16.h>

typedef __bf16 bf16x8  __attribute__((ext_vector_type(8)));
typedef float  f32x4   __attribute__((ext_vector_type(4)));
typedef float  f32x16  __attribute__((ext_vector_type(16)));

#define RSX 136            // x_t row stride (elems): 64 rows x 128 cols (+8 pad); rows 16B-aligned
#define RSH 264            // h_t row stride (elems): 64 rows x 256 cols (+8 pad)

// Streaming B layout for 32x32x16 MFMA:
//   WtB[cht(16)][chunk(108)][kstep(2)][ntile(2)][lane(64)][8 bf16]
//   cht   = octile*4 + wave (16 oc-tiles of 64 cols = 4 gates x 16 ch)
//   chunk = flattened K/32  (x: seg*4 + ic0/32 ; h: 36 + seg*8 + ic0/32)
//   global col (0..63) = gate*16 + oc  ->  ntile = gate>>1, c = (gate&1)*16 + oc
//   B-fragment (K=16 x N=32): lane = lh*32 + c holds k = kstep*16 + lh*8 + j
// Per wave-chunk: 4 loads, lane at base + 16B*lane -> contiguous 1KB bursts;
// consecutive chunks contiguous -> sequential 442KB stream per wave.
#define BCHT 221184        // 108*2048 ushorts per cht

__device__ __forceinline__ ushort f2bf(float f) {
    union { float f; uint i; } c; c.f = f;
    uint u = c.i;
    u = (u + 0x7fff + ((u >> 16) & 1)) >> 16;   // RTNE
    return (ushort)u;
}
// Clamped: exp arg bounded => no inf/NaN possible in the elementwise path.
__device__ __forceinline__ float sigmoidf_(float x) {
    x = fminf(fmaxf(x, -30.0f), 30.0f);
    return 1.0f / (1.0f + expf(-x));
}
__device__ __forceinline__ float tanhf_(float x) {
    x = fminf(fmaxf(x, -15.0f), 15.0f);
    const float e = expf(-2.0f * x);
    return (1.0f - e) / (1.0f + e);
}

// ---------------------------------------------------------------------------
// Prep: fp32 weights -> bf16 streaming-fragment layout WtB (32x32 fragments).
// ---------------------------------------------------------------------------
__global__ void prep_wt(const float* __restrict__ wii, const float* __restrict__ wif,
                        const float* __restrict__ wig, const float* __restrict__ wio,
                        const float* __restrict__ whi, const float* __restrict__ whf,
                        const float* __restrict__ whg, const float* __restrict__ who,
                        ushort* __restrict__ Wt) {
    const int idx = blockIdx.x * 256 + threadIdx.x;
    if (idx < 131072) {                       // x weights: 4 gates x 256 ch x 128 ic
        const int g   = idx >> 15;
        const int rem = idx & 32767;
        const int ch  = rem >> 7, ic = rem & 127;
        const float* w = (g == 0) ? wii : (g == 1) ? wif : (g == 2) ? wig : wio;
        const float* src = w + (size_t)(ch * 128 + ic) * 9;
        const int cht = ch >> 4;
        const int c   = ((g & 1) << 4) | (ch & 15);   // col within 32-wide n-tile
        ushort* dst = Wt + (size_t)cht * BCHT + (g >> 1) * 512 + c * 8;
        #pragma unroll
        for (int s = 0; s < 9; ++s) {
            const int k = s * 128 + ic;
            const int chunk = k >> 5, kstep = (k >> 4) & 1, lh = (k >> 3) & 1, j = k & 7;
            dst[chunk * 2048 + kstep * 1024 + lh * 256 + j] = f2bf(src[s]);
        }
    } else {                                  // h weights: 4 gates x 256 ch x 256 ic
        const int jj  = idx - 131072;
        const int g   = jj >> 16;
        const int rem = jj & 65535;
        const int ch  = rem >> 8, ic = rem & 255;
        const float* w = (g == 0) ? whi : (g == 1) ? whf : (g == 2) ? whg : who;
        const float* src = w + (size_t)(ch * 256 + ic) * 9;
        const int cht = ch >> 4;
        const int c   = ((g & 1) << 4) | (ch & 15);
        ushort* dst = Wt + (size_t)cht * BCHT + (g >> 1) * 512 + c * 8;
        #pragma unroll
        for (int s = 0; s < 9; ++s) {
            const int k = 1152 + s * 256 + ic;
            const int chunk = k >> 5, kstep = (k >> 4) & 1, lh = (k >> 3) & 1, j = k & 7;
            dst[chunk * 2048 + kstep * 1024 + lh * 256 + j] = f2bf(src[s]);
        }
    }
}

__global__ void prep_bias(const float* __restrict__ bii, const float* __restrict__ bif,
                          const float* __restrict__ big, const float* __restrict__ bio,
                          const float* __restrict__ bhi, const float* __restrict__ bhf,
                          const float* __restrict__ bhg, const float* __restrict__ bho,
                          float* __restrict__ btot) {
    const int g = blockIdx.x, ch = threadIdx.x;
    const float* bi = (g == 0) ? bii : (g == 1) ? bif : (g == 2) ? big : bio;
    const float* bh = (g == 0) ? bhi : (g == 1) ? bhf : (g == 2) ? bhg : bho;
    btot[g * 256 + ch] = bi[ch] + bh[ch];
}

#define MFMA32(A, B, C) __builtin_amdgcn_mfma_f32_32x32x16_bf16((A), (B), (C), 0, 0, 0)

// ---------------------------------------------------------------------------
// Main: one block = one image x 256 oc columns. fp32 in/out, bf16 MFMA core.
//  - 32x32x16 MFMA: 8 MFMA instructions per K=32 chunk (was 16 of 16x16x32)
//    at identical FLOPs, ds_read count, and B bytes. Targets the measured
//    invariant: ~48 SIMD-cyc per MFMA *instruction* across occupancy 2/3/4
//    waves/SIMD, 1x/0.5x B-traffic, and deep B-FIFO (R2/R3/R4/R7) -- a
//    per-instruction cost floor, not pipe/latency/bandwidth.
//  - A-frag: row=lane&31 (pixel, reflect-shifted), k=(lane>>5)*8; same
//    balanced 8-access/bank LDS profile as before.
//  - C/D (m74/m101-verified): col=lane&31, row=(reg&3)+8*(reg>>2)+4*(lane>>5).
//    col = gate*16+oc => lanes c and c^16 hold gates {i,g}/{f,o} of the SAME
//    channel & pixels -> epilogue pairs lanes via __shfl_xor(.,16).
//  - grid (octile=4, img=512): octile fast dim -> XCD-pinned Wt slice in L2
//  - TWO-PHASE LDS (33.8 KB): stage x -> x-taps -> re-stage h -> h-taps
//  - T5 setprio(1) around each MFMA cluster (role-diverse unsynced blocks).
// ---------------------------------------------------------------------------
__global__ __launch_bounds__(256, 3)
void convlstm_main(const float* __restrict__ x, const float* __restrict__ hidden,
                   const ushort* __restrict__ Wt, const float* __restrict__ btot,
                   const float* __restrict__ wci, const float* __restrict__ wcf,
                   const float* __restrict__ wco, float* __restrict__ out) {
    __shared__ alignas(16) ushort lds[64 * RSH];   // 33.8 KB

    const int octile = blockIdx.x;   // fast dim -> XCD-pinned
    const int img    = blockIdx.y;
    const int tid    = threadIdx.x;
    const int lane   = tid & 63;
    const int wave   = tid >> 6;
    const int l31    = lane & 31;
    const int lh8    = (lane >> 5) * 8;   // k-half offset within fragment

    f32x16 acc[2][2];   // [m_tile][n_tile]
    #pragma unroll
    for (int m = 0; m < 2; ++m)
        #pragma unroll
        for (int n = 0; n < 2; ++n)
            #pragma unroll
            for (int r = 0; r < 16; ++r) acc[m][n][r] = 0.0f;

    // B stream base: this wave's fragment-ordered weight region (442 KB, sequential)
    const ushort* Bw = Wt + (size_t)(octile * 4 + wave) * BCHT + (size_t)lane * 8;

    // ======== phase A: x ========
    // stage x: fp32 [ic][p] -> bf16 LDS [p][ic]; lanes along ic => conflict-free
    {
        const float* xs = x + img * 8192;
        #pragma unroll
        for (int it = 0; it < 4; ++it) {
            const int icp = lane;                // ic pair 0..63
            const int p0  = (it * 4 + wave) * 4; // pixel group
            const float4 f0 = *(const float4*)(xs + (2 * icp    ) * 64 + p0);
            const float4 f1 = *(const float4*)(xs + (2 * icp + 1) * 64 + p0);
            const float a0[4] = {f0.x, f0.y, f0.z, f0.w};
            const float a1[4] = {f1.x, f1.y, f1.z, f1.w};
            #pragma unroll
            for (int j = 0; j < 4; ++j) {
                const uint pk = (uint)f2bf(a0[j]) | ((uint)f2bf(a1[j]) << 16);
                *(uint*)(&lds[(p0 + j) * RSX + 2 * icp]) = pk;
            }
        }
    }
    __syncthreads();

    // x taps: 9 segments x 4 chunks (K=32 each)
    #pragma unroll 1
    for (int seg = 0; seg < 9; ++seg) {
        const int dy = seg / 3 - 1, dx = seg % 3 - 1;
        int aoff[2];
        #pragma unroll
        for (int m = 0; m < 2; ++m) {
            const int px = m * 32 + l31;
            const int yy = px >> 3, xx = px & 7;
            int sy = yy + dy; sy = (sy < 0) ? 1 : ((sy > 7) ? 6 : sy);
            int sx = xx + dx; sx = (sx < 0) ? 1 : ((sx > 7) ? 6 : sx);
            aoff[m] = (sy * 8 + sx) * RSX + lh8;
        }
        #pragma unroll
        for (int i = 0; i < 4; ++i) {
            const int ic0 = i * 32;
            const ushort* Bc = Bw + (size_t)(seg * 4 + i) * 2048;
            const bf16x8 a0k0 = *(const bf16x8*)(&lds[aoff[0] + ic0]);
            const bf16x8 a0k1 = *(const bf16x8*)(&lds[aoff[0] + ic0 + 16]);
            const bf16x8 a1k0 = *(const bf16x8*)(&lds[aoff[1] + ic0]);
            const bf16x8 a1k1 = *(const bf16x8*)(&lds[aoff[1] + ic0 + 16]);
            const bf16x8 b00 = *(const bf16x8*)(Bc);           // kstep0, ntile0
            const bf16x8 b01 = *(const bf16x8*)(Bc + 512);     // kstep0, ntile1
            const bf16x8 b10 = *(const bf16x8*)(Bc + 1024);    // kstep1, ntile0
            const bf16x8 b11 = *(const bf16x8*)(Bc + 1536);    // kstep1, ntile1
            __builtin_amdgcn_s_setprio(1);
            acc[0][0] = MFMA32(a0k0, b00, acc[0][0]);
            acc[0][1] = MFMA32(a0k0, b01, acc[0][1]);
            acc[1][0] = MFMA32(a1k0, b00, acc[1][0]);
            acc[1][1] = MFMA32(a1k0, b01, acc[1][1]);
            acc[0][0] = MFMA32(a0k1, b10, acc[0][0]);
            acc[0][1] = MFMA32(a0k1, b11, acc[0][1]);
            acc[1][0] = MFMA32(a1k1, b10, acc[1][0]);
            acc[1][1] = MFMA32(a1k1, b11, acc[1][1]);
            __builtin_amdgcn_s_setprio(0);
        }
    }

    // ======== phase B: h (re-stage same LDS buffer) ========
    __syncthreads();
    {
        const float* hs = hidden + img * 32768;   // h0 = hidden[img][0]
        #pragma unroll
        for (int it = 0; it < 8; ++it) {
            const int icp = (it & 1) * 64 + lane;       // ic pair 0..127
            const int p0  = ((it >> 1) * 4 + wave) * 4; // pixel group
            const float4 f0 = *(const float4*)(hs + (2 * icp    ) * 64 + p0);
            const float4 f1 = *(const float4*)(hs + (2 * icp + 1) * 64 + p0);
            const float a0[4] = {f0.x, f0.y, f0.z, f0.w};
            const float a1[4] = {f1.x, f1.y, f1.z, f1.w};
            #pragma unroll
            for (int j = 0; j < 4; ++j) {
                const uint pk = (uint)f2bf(a0[j]) | ((uint)f2bf(a1[j]) << 16);
                *(uint*)(&lds[(p0 + j) * RSH + 2 * icp]) = pk;
            }
        }
    }
    __syncthreads();

    // h taps: 9 segments x 8 chunks (K=32 each)
    #pragma unroll 1
    for (int seg = 0; seg < 9; ++seg) {
        const int dy = seg / 3 - 1, dx = seg % 3 - 1;
        int aoff[2];
        #pragma unroll
        for (int m = 0; m < 2; ++m) {
            const int px = m * 32 + l31;
            const int yy = px >> 3, xx = px & 7;
            int sy = yy + dy; sy = (sy < 0) ? 1 : ((sy > 7) ? 6 : sy);
            int sx = xx + dx; sx = (sx < 0) ? 1 : ((sx > 7) ? 6 : sx);
            aoff[m] = (sy * 8 + sx) * RSH + lh8;
        }
        #pragma unroll
        for (int i = 0; i < 8; ++i) {
            const int ic0 = i * 32;
            const ushort* Bc = Bw + (size_t)(36 + seg * 8 + i) * 2048;
            const bf16x8 a0k0 = *(const bf16x8*)(&lds[aoff[0] + ic0]);
            const bf16x8 a0k1 = *(const bf16x8*)(&lds[aoff[0] + ic0 + 16]);
            const bf16x8 a1k0 = *(const bf16x8*)(&lds[aoff[1] + ic0]);
            const bf16x8 a1k1 = *(const bf16x8*)(&lds[aoff[1] + ic0 + 16]);
            const bf16x8 b00 = *(const bf16x8*)(Bc);
            const bf16x8 b01 = *(const bf16x8*)(Bc + 512);
            const bf16x8 b10 = *(const bf16x8*)(Bc + 1024);
            const bf16x8 b11 = *(const bf16x8*)(Bc + 1536);
            __builtin_amdgcn_s_setprio(1);
            acc[0][0] = MFMA32(a0k0, b00, acc[0][0]);
            acc[0][1] = MFMA32(a0k0, b01, acc[0][1]);
            acc[1][0] = MFMA32(a1k0, b00, acc[1][0]);
            acc[1][1] = MFMA32(a1k0, b01, acc[1][1]);
            acc[0][0] = MFMA32(a0k1, b10, acc[0][0]);
            acc[0][1] = MFMA32(a0k1, b11, acc[0][1]);
            acc[1][0] = MFMA32(a1k1, b10, acc[1][0]);
            acc[1][1] = MFMA32(a1k1, b11, acc[1][1]);
            __builtin_amdgcn_s_setprio(0);
        }
    }

    // ---- fused LSTM epilogue, fp32 I/O.
    // Lane c holds gates {c>>4, (c>>4)+2} of channel oc=c&15 (t0/t1 n-tiles);
    // partner lane c^16 holds the complementary pair for the SAME oc & pixels.
    const int oc = l31 & 15;
    const int ga = l31 >> 4;          // 0: holds (i,g); 1: holds (f,o)
    const int hi = lane >> 5;
    const int ch = (octile * 4 + wave) * 16 + oc;

    const float* h0p = hidden + img * 32768 + ch * 64;
    const float* c0p = h0p + 16384;
    const float* wip = wci + ch * 64;
    const float* wfp = wcf + ch * 64;
    const float* wop = wco + ch * 64;
    const float bi_ = btot[      ch];
    const float bf_ = btot[256 + ch];
    const float bg_ = btot[512 + ch];
    const float bo_ = btot[768 + ch];

    float* o_out = out + img * 16384 + ch * 64;
    float* h_out = out + 8388608 + img * 32768 + ch * 64;   // hidden_out[img][0]
    float* c_out = h_out + 16384;                           // hidden_out[img][1]

    #pragma unroll
    for (int m = 0; m < 2; ++m) {
        #pragma unroll
        for (int q = 0; q < 4; ++q) {
            const int P0 = m * 32 + q * 8 + hi * 4;   // 4 consecutive pixels (r=0..3)
            union { float4 v; float f[4]; } c0u, h0u, wiu, wfu, wou, ov4, hv4, cv4;
            c0u.v = *(const float4*)(c0p + P0);
            h0u.v = *(const float4*)(h0p + P0);
            wiu.v = *(const float4*)(wip + P0);
            wfu.v = *(const float4*)(wfp + P0);
            wou.v = *(const float4*)(wop + P0);
            #pragma unroll
            for (int r = 0; r < 4; ++r) {
                const float own0 = acc[m][0][q * 4 + r];
                const float own1 = acc[m][1][q * 4 + r];
                const float rec0 = __shfl_xor(own0, 16, 64);
                const float rec1 = __shfl_xor(own1, 16, 64);
                const float gi = (ga ? rec0 : own0) + bi_;
                const float gf = (ga ? own0 : rec0) + bf_;
                const float gg = (ga ? rec1 : own1) + bg_;
                const float go = (ga ? own1 : rec1) + bo_;
                const float c0v = c0u.f[r];
                const float h0v = h0u.f[r];
                const float iv = sigmoidf_(gi + c0v * wiu.f[r]);
                const float fv = sigmoidf_(gf + c0v * wfu.f[r]);
                const float gv = tanhf_(gg);
                const float ct = c0v + fv * c0v + iv * gv;
                const float ov = sigmoidf_(go + ct * wou.f[r]);
                const float ht = h0v + ov * tanhf_(ct);
                ov4.f[r] = ov;
                hv4.f[r] = ht;
                cv4.f[r] = ct;
            }
            if (ga == 0) {                       // one lane of each pair stores
                *(float4*)(o_out + P0) = ov4.v;
                *(float4*)(h_out + P0) = hv4.v;
            } else {
                *(float4*)(c_out + P0) = cv4.v;
            }
        }
    }
}

extern "C" void kernel_launch(void* const* d_in, const int* in_sizes, int n_in,
                              void* d_out, int out_size, void* d_ws, size_t ws_size,
                              hipStream_t stream) {
    const float* x      = (const float*)d_in[0];
    const float* hidden = (const float*)d_in[1];
    const float* wii = (const float*)d_in[2];  const float* bii = (const float*)d_in[3];
    const float* wif = (const float*)d_in[4];  const float* bif = (const float*)d_in[5];
    const float* wig = (const float*)d_in[6];  const float* big = (const float*)d_in[7];
    const float* wio = (const float*)d_in[8];  const float* bio = (const float*)d_in[9];
    const float* whi = (const float*)d_in[10]; const float* bhi = (const float*)d_in[11];
    const float* whf = (const float*)d_in[12]; const float* bhf = (const float*)d_in[13];
    const float* whg = (const float*)d_in[14]; const float* bhg = (const float*)d_in[15];
    const float* who = (const float*)d_in[16]; const float* bho = (const float*)d_in[17];
    const float* wci = (const float*)d_in[18];
    const float* wcf = (const float*)d_in[19];
    const float* wco = (const float*)d_in[20];

    ushort* Wt  = (ushort*)d_ws;                               // 16*221184 bf16 = 6.75 MiB
    float* btot = (float*)((char*)d_ws + (size_t)16 * BCHT * 2);

    prep_wt<<<dim3(1536), 256, 0, stream>>>(wii, wif, wig, wio, whi, whf, whg, who, Wt);
    prep_bias<<<dim3(4), 256, 0, stream>>>(bii, bif, big, bio, bhi, bhf, bhg, bho, btot);
    convlstm_main<<<dim3(4, 512), 256, 0, stream>>>(x, hidden, Wt, btot, wci, wcf, wco,
                                                    (float*)d_out);
}